// Round 2
// baseline (118862.805 us; speedup 1.0000x reference)
//
#include <hip/hip_runtime.h>
#include <math.h>

// Problem constants
constexpr int H   = 256;
constexpr int B   = 64;
constexpr int T   = 2048;
constexpr int G   = 64;    // blocks
constexpr int NTH = 512;   // threads per block (8 waves)
constexpr int HB  = H * B; // 16384

struct SharedMain {
    float wU[256][16];   // W_ih slice, [k][cl], cl = gate*4+oi
    float wV[256][16];   // W_hh slice
    float wA[768][4];    // W_e (rows 0..511) + W_b (rows 512..767), [r][i]
    float U[2][64][17];  // x@W_ih^T partials, double-buffered across steps
    float aX[2][64][5];  // x-part of 'a', double-buffered
    float V[64][17];     // h@W_hh^T
    float aH[64][5];     // hc-part of 'a'
    alignas(16) float outst[64][4];  // output staging for float4 store
    float jp[8][64];     // per-wave j partial sums
    float cloc[4][64];   // local copy of our own 4 c-columns
    float bg[16];        // b_ih+b_hh slice
    float ba[4];         // b_e+b_b slice
    float v4[4];         // v_b slice
    float s[64];         // softmax weights
};
union SharedAll {
    SharedMain m;
    float tile[64][65];  // transpose staging (aliases weight region; used first)
};

__device__ __forceinline__ float sigmoidf_(float v) {
    return 1.0f / (1.0f + expf(-v));
}

// LLC-coherent scalar access (bypasses non-coherent L1/L2 via sc bits; no fences)
__device__ __forceinline__ float gload(const float* p) {
    return __hip_atomic_load(p, __ATOMIC_RELAXED, __HIP_MEMORY_SCOPE_AGENT);
}
__device__ __forceinline__ void gstore(float* p, float v) {
    __hip_atomic_store(p, v, __ATOMIC_RELAXED, __HIP_MEMORY_SCOPE_AGENT);
}

// One-time heavy barrier: publishes plain-stored xT / h,c zeros (needs wbl2+inv).
__device__ __forceinline__ void grid_barrier_full(unsigned* bar, unsigned target) {
    __syncthreads();
    if (threadIdx.x == 0) {
        __threadfence();
        __hip_atomic_fetch_add(bar, 1u, __ATOMIC_ACQ_REL, __HIP_MEMORY_SCOPE_AGENT);
        while (__hip_atomic_load(bar, __ATOMIC_ACQUIRE, __HIP_MEMORY_SCOPE_AGENT) < target) {
            __builtin_amdgcn_s_sleep(1);
        }
        __threadfence();
    }
    __syncthreads();
}

// Light epoch barrier: all cross-block data moves via agent-scope (LLC) accesses,
// and __syncthreads drains vmcnt per wave before the arrive, so NO cache
// maintenance (buffer_wbl2 / buffer_inv) is needed — that was the 44 us/step.
__device__ __forceinline__ void epoch_wait(unsigned* bar, unsigned target) {
    if (threadIdx.x == 0) {
        while (__hip_atomic_load(bar, __ATOMIC_RELAXED, __HIP_MEMORY_SCOPE_AGENT) < target) {
            __builtin_amdgcn_s_sleep(1);
        }
    }
    __syncthreads();
}
__device__ __forceinline__ void epoch_arrive(unsigned* bar) {
    // call from thread 0 only, immediately after a __syncthreads()
    __hip_atomic_fetch_add(bar, 1u, __ATOMIC_RELAXED, __HIP_MEMORY_SCOPE_AGENT);
}

__global__ void __launch_bounds__(NTH, 1)
scan_kernel(const float* __restrict__ x,
            const float* __restrict__ W_b,  const float* __restrict__ b_b,
            const float* __restrict__ v_b,  const float* __restrict__ W_e,
            const float* __restrict__ b_e,  const float* __restrict__ W_ih,
            const float* __restrict__ W_hh, const float* __restrict__ b_ih,
            const float* __restrict__ b_hh,
            float* __restrict__ out, float* __restrict__ wsf,
            unsigned* __restrict__ bar)
{
    __shared__ SharedAll sh;
    const int tid = threadIdx.x;
    const int g   = blockIdx.x;
    const int wv  = tid >> 6;   // wave 0..7
    const int b   = tid & 63;   // lane = batch index

    float* pJ = wsf + 64;        // [G][64] j partials, 256B offset from bar
    float* hT = pJ + G * 64;     // [H][B] transposed h state
    float* cT = hT + HB;         // [H][B] transposed c state
    float* xT = out;             // reuse output buffer: xT[t] dead before out[t] written

    // ---------- Phase 0: transpose x[t][b][k] -> xT[t][k][b] (plain stores) ----------
    for (int tl = g; tl < T * 4; tl += G) {
        const int t  = tl >> 2;
        const int kc = (tl & 3) << 6;
        __syncthreads();
        for (int q = tid; q < 1024; q += NTH) {
            const int r  = q >> 4;
            const int c4 = (q & 15) << 2;
            const float4 v = *(const float4*)(x + (size_t)t * HB + (size_t)r * H + kc + c4);
            sh.tile[r][c4 + 0] = v.x; sh.tile[r][c4 + 1] = v.y;
            sh.tile[r][c4 + 2] = v.z; sh.tile[r][c4 + 3] = v.w;
        }
        __syncthreads();
        for (int q = tid; q < 1024; q += NTH) {
            const int k  = q >> 4;
            const int b4 = (q & 15) << 2;
            float4 v;
            v.x = sh.tile[b4 + 0][k]; v.y = sh.tile[b4 + 1][k];
            v.z = sh.tile[b4 + 2][k]; v.w = sh.tile[b4 + 3][k];
            *(float4*)(xT + (size_t)t * HB + (size_t)(kc + k) * B + b4) = v;
        }
    }
    __syncthreads();

    // ---------- Phase 1: weights -> LDS (block owns h-cols 4g..4g+3) ----------
    for (int e = tid; e < 256 * 16; e += NTH) {
        const int k  = e >> 4;
        const int cl = e & 15;
        const int gate = cl >> 2, oi = cl & 3;
        const int row = gate * H + 4 * g + oi;
        sh.m.wU[k][cl] = W_ih[(size_t)row * H + k];
        sh.m.wV[k][cl] = W_hh[(size_t)row * H + k];
    }
    for (int e = tid; e < 768 * 4; e += NTH) {
        const int r = e >> 2;
        const int i = e & 3;
        const int col = 4 * g + i;
        float w;
        if (r < 512) w = W_e[(size_t)col * 512 + r];
        else         w = W_b[(size_t)col * 256 + (r - 512)];
        sh.m.wA[r][i] = w;
    }
    if (tid < 16) {
        const int gate = tid >> 2, oi = tid & 3;
        const int col = gate * H + 4 * g + oi;
        sh.m.bg[tid] = b_ih[col] + b_hh[col];
    }
    if (tid < 4) {
        sh.m.ba[tid] = b_e[4 * g + tid] + b_b[4 * g + tid];
        sh.m.v4[tid] = v_b[4 * g + tid];
    }
    // zero h,c (hT and cT are contiguous: 32768 floats == G*NTH)
    hT[g * NTH + tid] = 0.0f;

    // publish xT + zeroed state once (epoch 1)
    grid_barrier_full(bar, (unsigned)G);

    // ---------- helpers for the x-dependent (recurrence-free) pass ----------
    auto x_zero = [&](int p) {
        for (int e = tid; e < 64 * 17; e += NTH) (&sh.m.U[p][0][0])[e] = 0.0f;
        for (int e = tid; e < 64 * 5;  e += NTH) (&sh.m.aX[p][0][0])[e] = 0.0f;
    };
    auto x_accum = [&](int t, int p, int half) {
        const int krow = (wv << 4) + (half << 7);  // 16 k per wave per half
        const float* src = xT + (size_t)t * HB + (size_t)krow * B;
        float aU[16], aA[4];
        #pragma unroll
        for (int c = 0; c < 16; ++c) aU[c] = 0.0f;
        aA[0] = aA[1] = aA[2] = aA[3] = 0.0f;
        #pragma unroll 4
        for (int kk = 0; kk < 16; ++kk) {
            const float xv = src[kk * B + b];      // plain load: L2-cacheable, never rewritten
            const float* wr = sh.m.wU[krow + kk];
            #pragma unroll
            for (int c = 0; c < 16; ++c) aU[c] = fmaf(xv, wr[c], aU[c]);
            const float* wa = sh.m.wA[512 + krow + kk];
            #pragma unroll
            for (int i = 0; i < 4; ++i) aA[i] = fmaf(xv, wa[i], aA[i]);
        }
        #pragma unroll
        for (int c = 0; c < 16; ++c) atomicAdd(&sh.m.U[p][b][c], aU[c]);
        #pragma unroll
        for (int i = 0; i < 4; ++i) atomicAdd(&sh.m.aX[p][b][i], aA[i]);
    };

    // ---------- prologue ----------
    int par = 0;
    if (tid < 256) sh.m.cloc[tid >> 6][tid & 63] = 0.0f;
    for (int e = tid; e < 64 * 17; e += NTH) (&sh.m.V[0][0])[e] = 0.0f;
    for (int e = tid; e < 64 * 5;  e += NTH) (&sh.m.aH[0][0])[e] = 0.0f;
    x_zero(0);
    __syncthreads();
    x_accum(0, 0, 0);
    x_accum(0, 0, 1);

    // ---------- Main scan ----------
    // epochs: heavy=1; step t: bar1 (pJ ready) = 2t+2, bar2 (h,c ready) = 2t+3
    for (int t = 0; t < T; ++t) {
        if (t > 0) epoch_wait(bar, (unsigned)(2 * t + 1) * G);

        // fused: V = h@W_hh^T slice  +  hc-part of 'a' (one pass over h,c via LLC)
        {
            const int krow = wv << 5;              // 32 k per wave
            const float* sHp = hT + (size_t)krow * B;
            const float* sCp = cT + (size_t)krow * B;
            float aV[16], aA[4];
            #pragma unroll
            for (int c = 0; c < 16; ++c) aV[c] = 0.0f;
            aA[0] = aA[1] = aA[2] = aA[3] = 0.0f;
            #pragma unroll 8
            for (int kk = 0; kk < 32; ++kk) {
                const float hv = gload(sHp + kk * B + b);
                const float cv = gload(sCp + kk * B + b);
                const float* wr = sh.m.wV[krow + kk];
                #pragma unroll
                for (int c = 0; c < 16; ++c) aV[c] = fmaf(hv, wr[c], aV[c]);
                const float* waH = sh.m.wA[krow + kk];
                const float* waC = sh.m.wA[256 + krow + kk];
                #pragma unroll
                for (int i = 0; i < 4; ++i) aA[i] = fmaf(hv, waH[i], fmaf(cv, waC[i], aA[i]));
            }
            #pragma unroll
            for (int c = 0; c < 16; ++c) atomicAdd(&sh.m.V[b][c], aV[c]);
            #pragma unroll
            for (int i = 0; i < 4; ++i) atomicAdd(&sh.m.aH[b][i], aA[i]);
        }
        __syncthreads();

        // finish 'a': tanh, dot with v -> per-block j partial (agent store)
        if (tid < 64) {
            float pj = 0.0f;
            #pragma unroll
            for (int i = 0; i < 4; ++i)
                pj += tanhf(sh.m.aX[par][tid][i] + sh.m.aH[tid][i] + sh.m.ba[i]) * sh.m.v4[i];
            gstore(&pJ[g * 64 + tid], pj);
        }
        __syncthreads();                           // drains the pJ stores (vmcnt)
        if (tid == 0) epoch_arrive(bar);           // epoch 2t+2

        // bar1 shadow: first half of next step's x-dependent pass
        if (t + 1 < T) { x_zero(par ^ 1); __syncthreads(); x_accum(t + 1, par ^ 1, 0); }

        epoch_wait(bar, (unsigned)(2 * t + 2) * G);

        // j reduction (all waves, agent loads), then softmax over batch (wave 0)
        {
            float jpart = 0.0f;
            const int base = wv * 8;
            #pragma unroll
            for (int gg = 0; gg < 8; ++gg) jpart += gload(&pJ[(base + gg) * 64 + b]);
            sh.m.jp[wv][b] = jpart;
        }
        __syncthreads();
        if (tid < 64) {
            float jv = 0.0f;
            #pragma unroll
            for (int w = 0; w < 8; ++w) jv += sh.m.jp[w][tid];
            float mx = jv;
            #pragma unroll
            for (int off = 32; off; off >>= 1) mx = fmaxf(mx, __shfl_xor(mx, off));
            const float e = expf(jv - mx);
            float ssum = e;
            #pragma unroll
            for (int off = 32; off; off >>= 1) ssum += __shfl_xor(ssum, off);
            sh.m.s[tid] = e / ssum;
        }
        __syncthreads();

        // gates + LSTM cell update for our 4 h-columns (own c cached in LDS)
        if (tid < 256) {
            const int oi = tid >> 6;
            const int bb = tid & 63;
            const float sb = sh.m.s[bb];
            const float* Ur = sh.m.U[par][bb];
            const float* Vr = sh.m.V[bb];
            const float pI = fmaf(sb, Ur[0  + oi], Vr[0  + oi]) + sh.m.bg[0  + oi];
            const float pF = fmaf(sb, Ur[4  + oi], Vr[4  + oi]) + sh.m.bg[4  + oi];
            const float pG = fmaf(sb, Ur[8  + oi], Vr[8  + oi]) + sh.m.bg[8  + oi];
            const float pO = fmaf(sb, Ur[12 + oi], Vr[12 + oi]) + sh.m.bg[12 + oi];
            const int col = 4 * g + oi;
            const float cold = sh.m.cloc[oi][bb];
            const float cnew = sigmoidf_(pF) * cold + sigmoidf_(pI) * tanhf(pG);
            const float hnew = sigmoidf_(pO) * tanhf(cnew);
            sh.m.cloc[oi][bb] = cnew;
            gstore(&cT[(size_t)col * B + bb], cnew);
            gstore(&hT[(size_t)col * B + bb], hnew);
            sh.m.outst[bb][oi] = hnew;
        }
        __syncthreads();                           // drains h/c agent stores (vmcnt)

        // tail: output store (plain; nobody reads out[t] cross-block) + zero V/aH
        if (tid < 64) {
            const float4 v = *(const float4*)sh.m.outst[tid];
            *(float4*)(out + (size_t)t * HB + (size_t)tid * H + 4 * g) = v;
        }
        for (int e = tid; e < 64 * 17; e += NTH) (&sh.m.V[0][0])[e] = 0.0f;
        for (int e = tid; e < 64 * 5;  e += NTH) (&sh.m.aH[0][0])[e] = 0.0f;
        __syncthreads();
        if (tid == 0) epoch_arrive(bar);           // epoch 2t+3

        // bar2 shadow: second half of next step's x-dependent pass
        if (t + 1 < T) x_accum(t + 1, par ^ 1, 1);
        par ^= 1;
    }
}

extern "C" void kernel_launch(void* const* d_in, const int* in_sizes, int n_in,
                              void* d_out, int out_size, void* d_ws, size_t ws_size,
                              hipStream_t stream) {
    const float* x    = (const float*)d_in[0];
    const float* W_b  = (const float*)d_in[1];
    const float* b_b  = (const float*)d_in[2];
    const float* v_b  = (const float*)d_in[3];
    const float* W_e  = (const float*)d_in[4];
    const float* b_e  = (const float*)d_in[5];
    const float* W_ih = (const float*)d_in[6];
    const float* W_hh = (const float*)d_in[7];
    const float* b_ih = (const float*)d_in[8];
    const float* b_hh = (const float*)d_in[9];
    float*    out = (float*)d_out;
    float*    wsf = (float*)d_ws;
    unsigned* bar = (unsigned*)d_ws;

    // zero the barrier counter (ws is poisoned before every launch)
    hipMemsetAsync(d_ws, 0, 256, stream);

    void* args[] = { &x, &W_b, &b_b, &v_b, &W_e, &b_e, &W_ih, &W_hh, &b_ih, &b_hh,
                     &out, &wsf, &bar };
    hipLaunchCooperativeKernel((void*)scan_kernel, dim3(G), dim3(NTH), args, 0, stream);
}

// Round 3
// 114822.864 us; speedup vs baseline: 1.0352x; 1.0352x over previous
//
#include <hip/hip_runtime.h>
#include <math.h>

// Problem constants
constexpr int H   = 256;
constexpr int B   = 64;
constexpr int T   = 2048;
constexpr int G   = 64;    // one block per batch row
constexpr int NTH = 1024;  // 16 waves
constexpr int HB  = H * B;

// Batch-partitioned design: block g owns batch row g. h,c live in LDS for the
// whole kernel. The only cross-block traffic per step is one tagged 8-byte
// j-value per block (softmax over batch). Weights stream from per-XCD L2
// every step via an octet pattern: 8 lanes x float4 = one full 128B line per
// row per instruction (fully consumed immediately -> no L1 retention needed,
// no over-fetch, perfectly coalesced).
struct Sh {
    float h[H];        // own row's h state (persistent across steps)
    float c[H];        // own row's c state
    float xv[2][H];    // x_t staging (double-buffered)
    float bx[2][H];    // x@W_b^T (double-buffered, computed in shadow)
    float a_s[H];      // [h,c]@W_e^T
    float Ux[4*H];     // x@W_ih^T
    float Vh[4*H];     // h@W_hh^T
    float bg[4*H];     // b_ih + b_hh
    float ba[H];       // b_e + b_b
    float vb[H];       // v_b
    float jp[4];       // per-wave j partials (waves 0..3)
    float sb;          // own softmax weight
};

__device__ __forceinline__ float sigmoidf_(float v) { return 1.0f / (1.0f + expf(-v)); }

__device__ __forceinline__ float dot4(float4 w, float4 m, float acc) {
    acc = fmaf(w.x, m.x, acc);
    acc = fmaf(w.y, m.y, acc);
    acc = fmaf(w.z, m.z, acc);
    acc = fmaf(w.w, m.w, acc);
    return acc;
}

__global__ void __launch_bounds__(NTH, 1)
scan_kernel(const float* __restrict__ x,
            const float* __restrict__ W_b,  const float* __restrict__ b_b,
            const float* __restrict__ v_b,  const float* __restrict__ W_e,
            const float* __restrict__ b_e,  const float* __restrict__ W_ih,
            const float* __restrict__ W_hh, const float* __restrict__ b_ih,
            const float* __restrict__ b_hh,
            float* __restrict__ out,
            unsigned long long* __restrict__ slot)   // [2][G] tagged j-slots in ws
{
    __shared__ Sh sh;
    const int tid  = threadIdx.x;
    const int g    = blockIdx.x;   // owned batch row
    const int wv   = tid >> 6;     // wave 0..15
    const int lane = tid & 63;
    const int oct  = lane >> 3;    // row-octet within wave
    const int q    = lane & 7;     // lane within octet (k-position)

    // ---------- prologue: biases, state, x[0], bx[0] ----------
    sh.bg[tid] = b_ih[tid] + b_hh[tid];          // NTH == 4H exactly
    if (tid < H) {
        sh.h[tid] = 0.0f; sh.c[tid] = 0.0f;
        sh.ba[tid] = b_e[tid] + b_b[tid];
        sh.vb[tid] = v_b[tid];
    }
    if (tid < 64) {
        float4 v = *(const float4*)(x + (size_t)g * H + (size_t)tid * 4);
        *(float4*)&sh.xv[0][tid * 4] = v;
    }
    __syncthreads();
    {   // bx[0] = x_0 @ W_b^T  (256 rows x 256 k)
        const float4* xv4 = (const float4*)sh.xv[0];
        #pragma unroll
        for (int p = 0; p < 2; ++p) {
            const int r = wv * 16 + p * 8 + oct;
            const float4* wr4 = (const float4*)(W_b + (size_t)r * H);
            float acc = 0.0f;
            #pragma unroll
            for (int j = 0; j < 8; ++j)
                acc = dot4(wr4[j * 8 + q], xv4[j * 8 + q], acc);
            acc += __shfl_xor(acc, 1); acc += __shfl_xor(acc, 2); acc += __shfl_xor(acc, 4);
            if (q == 0) sh.bx[0][r] = acc;
        }
    }
    __syncthreads();

    int par = 0;
    for (int t = 0; t < T; ++t) {
        // ---- Phase A (critical): a = [h,c] @ W_e^T  (256 rows x 512 k) ----
        {
            const float4* hv4 = (const float4*)sh.h;
            const float4* cv4 = (const float4*)sh.c;
            #pragma unroll
            for (int p = 0; p < 2; ++p) {
                const int r = wv * 16 + p * 8 + oct;
                const float4* wr4 = (const float4*)(W_e + (size_t)r * (2 * H));
                float acc = 0.0f;
                #pragma unroll
                for (int j = 0; j < 8; ++j)
                    acc = dot4(wr4[j * 8 + q], hv4[j * 8 + q], acc);
                #pragma unroll
                for (int j = 0; j < 8; ++j)
                    acc = dot4(wr4[64 + j * 8 + q], cv4[j * 8 + q], acc);
                acc += __shfl_xor(acc, 1); acc += __shfl_xor(acc, 2); acc += __shfl_xor(acc, 4);
                if (q == 0) sh.a_s[r] = acc;
            }
        }
        __syncthreads();
        // finish j: tanh + dot v_b, wave butterflies then 4-way sum
        if (tid < H) {
            float tv = tanhf(sh.a_s[tid] + sh.bx[par][tid] + sh.ba[tid]) * sh.vb[tid];
            #pragma unroll
            for (int off = 32; off; off >>= 1) tv += __shfl_xor(tv, off);
            if (lane == 0) sh.jp[wv] = tv;
        }
        __syncthreads();
        if (tid == 0) {
            float jv = sh.jp[0] + sh.jp[1] + sh.jp[2] + sh.jp[3];
            unsigned long long u = ((unsigned long long)(unsigned)(t + 1) << 32)
                                 | (unsigned long long)__float_as_uint(jv);
            __hip_atomic_store(&slot[(size_t)(t & 1) * G + g], u,
                               __ATOMIC_RELAXED, __HIP_MEMORY_SCOPE_AGENT);
        }

        // ---- Phase B (shadow of the j exchange): Ux, Vh, next bx, next x ----
        const int parn = par ^ 1;
        const int tn = (t + 1 < T) ? (t + 1) : t;   // last step: harmless reload
        if (tid < 64) {
            float4 v = *(const float4*)(x + ((size_t)tn * B + g) * H + (size_t)tid * 4);
            *(float4*)&sh.xv[parn][tid * 4] = v;
        }
        {   // Ux = x_t @ W_ih^T ; Vh = h @ W_hh^T   (1024 rows x 256 k each)
            const float4* xv4 = (const float4*)sh.xv[par];
            const float4* hv4 = (const float4*)sh.h;
            #pragma unroll 2
            for (int p = 0; p < 8; ++p) {
                const int r = wv * 64 + p * 8 + oct;
                const float4* wi4 = (const float4*)(W_ih + (size_t)r * H);
                const float4* wh4 = (const float4*)(W_hh + (size_t)r * H);
                float aU = 0.0f, aV = 0.0f;
                #pragma unroll
                for (int j = 0; j < 8; ++j) {
                    const float4 xm = xv4[j * 8 + q];
                    const float4 hm = hv4[j * 8 + q];
                    aU = dot4(wi4[j * 8 + q], xm, aU);
                    aV = dot4(wh4[j * 8 + q], hm, aV);
                }
                aU += __shfl_xor(aU, 1); aU += __shfl_xor(aU, 2); aU += __shfl_xor(aU, 4);
                aV += __shfl_xor(aV, 1); aV += __shfl_xor(aV, 2); aV += __shfl_xor(aV, 4);
                if (q == 0) { sh.Ux[r] = aU; sh.Vh[r] = aV; }
            }
        }
        __syncthreads();   // xv[parn] staged; Ux/Vh complete
        {   // bx[parn] = x_{t+1} @ W_b^T
            const float4* xv4 = (const float4*)sh.xv[parn];
            #pragma unroll
            for (int p = 0; p < 2; ++p) {
                const int r = wv * 16 + p * 8 + oct;
                const float4* wr4 = (const float4*)(W_b + (size_t)r * H);
                float acc = 0.0f;
                #pragma unroll
                for (int j = 0; j < 8; ++j)
                    acc = dot4(wr4[j * 8 + q], xv4[j * 8 + q], acc);
                acc += __shfl_xor(acc, 1); acc += __shfl_xor(acc, 2); acc += __shfl_xor(acc, 4);
                if (q == 0) sh.bx[parn][r] = acc;
            }
        }

        // ---- Phase C: wave 0 polls the 64 tagged j's, computes softmax ----
        // Overwrite-safety: slot[t&1][X] is next rewritten at step t+2, which
        // requires X to pass step t+1's poll, which requires every block's
        // t+1-publish, which requires every block's step-t poll to succeed.
        if (wv == 0) {
            const unsigned want = (unsigned)(t + 1);
            unsigned long long u;
            for (;;) {
                u = __hip_atomic_load(&slot[(size_t)(t & 1) * G + lane],
                                      __ATOMIC_RELAXED, __HIP_MEMORY_SCOPE_AGENT);
                if (__all((int)((unsigned)(u >> 32) == want))) break;
                __builtin_amdgcn_s_sleep(1);
            }
            float jv = __uint_as_float((unsigned)u);
            float mx = jv;
            #pragma unroll
            for (int off = 32; off; off >>= 1) mx = fmaxf(mx, __shfl_xor(mx, off));
            float e = expf(jv - mx);
            float ss = e;
            #pragma unroll
            for (int off = 32; off; off >>= 1) ss += __shfl_xor(ss, off);
            float sv = __shfl(e, g) / ss;   // own softmax weight (all lanes)
            if (lane == 0) sh.sb = sv;
        }
        __syncthreads();   // joins B writes + sb

        // ---- Phase D: gates + LSTM cell update (all state local) ----
        if (tid < H) {
            const float sbv = sh.sb;
            const int n = tid;
            const float gi = fmaf(sbv, sh.Ux[n        ], sh.Vh[n        ]) + sh.bg[n        ];
            const float gf = fmaf(sbv, sh.Ux[n +     H], sh.Vh[n +     H]) + sh.bg[n +     H];
            const float gG = fmaf(sbv, sh.Ux[n + 2 * H], sh.Vh[n + 2 * H]) + sh.bg[n + 2 * H];
            const float go = fmaf(sbv, sh.Ux[n + 3 * H], sh.Vh[n + 3 * H]) + sh.bg[n + 3 * H];
            const float cnew = sigmoidf_(gf) * sh.c[n] + sigmoidf_(gi) * tanhf(gG);
            const float hnew = sigmoidf_(go) * tanhf(cnew);
            sh.c[n] = cnew; sh.h[n] = hnew;
            out[(size_t)t * HB + (size_t)g * H + n] = hnew;  // coalesced 1KB
        }
        __syncthreads();   // h,c visible for next Phase A; LDS buffers reusable
        par = parn;
    }
}

extern "C" void kernel_launch(void* const* d_in, const int* in_sizes, int n_in,
                              void* d_out, int out_size, void* d_ws, size_t ws_size,
                              hipStream_t stream) {
    const float* x    = (const float*)d_in[0];
    const float* W_b  = (const float*)d_in[1];
    const float* b_b  = (const float*)d_in[2];
    const float* v_b  = (const float*)d_in[3];
    const float* W_e  = (const float*)d_in[4];
    const float* b_e  = (const float*)d_in[5];
    const float* W_ih = (const float*)d_in[6];
    const float* W_hh = (const float*)d_in[7];
    const float* b_ih = (const float*)d_in[8];
    const float* b_hh = (const float*)d_in[9];
    float* out = (float*)d_out;
    unsigned long long* slot = (unsigned long long*)d_ws;

    // zero the tagged j-slots (2*64*8B); tags start at 1 each launch
    hipMemsetAsync(d_ws, 0, 1024, stream);

    void* args[] = { &x, &W_b, &b_b, &v_b, &W_e, &b_e, &W_ih, &W_hh, &b_ih, &b_hh,
                     &out, &slot };
    hipLaunchCooperativeKernel((void*)scan_kernel, dim3(G), dim3(NTH), args, 0, stream);
}